// Round 3
// baseline (20212.061 us; speedup 1.0000x reference)
//
#include <hip/hip_runtime.h>
#include <hip/hip_fp16.h>
#include <math.h>

// Problem dims
#define T_STEPS 1024
#define BATCH   128
#define D_IN    256
#define H_DIM   256
#define NCOL    1024  // 4 gates * H
#define RING    4     // x-producer ring depth (steps ahead)

typedef _Float16 half2_t __attribute__((ext_vector_type(2)));

__device__ __forceinline__ float sigmoidf_(float x) {
    return 1.0f / (1.0f + __expf(-x));
}

__device__ __forceinline__ float tanhf_(float x) {
    float ax = fabsf(x);
    float t = __expf(-2.0f * ax);
    float r = (1.0f - t) / (1.0f + t);
    return copysignf(r, x);
}

// 2-way f16 dot with f32 accumulate: acc += w.x*h.x + w.y*h.y
__device__ __forceinline__ float dot2f(unsigned int w, unsigned int h, float acc) {
#if __has_builtin(__builtin_amdgcn_fdot2)
    return __builtin_amdgcn_fdot2(__builtin_bit_cast(half2_t, w),
                                  __builtin_bit_cast(half2_t, h), acc, false);
#else
    __half2 wv = *(__half2*)&w, hv = *(__half2*)&h;
    acc = fmaf(__half2float(wv.x), __half2float(hv.x), acc);
    return fmaf(__half2float(wv.y), __half2float(hv.y), acc);
#endif
}

__device__ __forceinline__ unsigned int packh2(float a, float b) {
    __half2 p = __floats2half2_rn(a, b);
    return *(unsigned int*)&p;
}

__device__ __forceinline__ uint4 pack8(const float* p) {
    return make_uint4(packh2(p[0], p[1]), packh2(p[2], p[3]),
                      packh2(p[4], p[5]), packh2(p[6], p[7]));
}

#define AQ __HIP_MEMORY_SCOPE_AGENT
__device__ __forceinline__ void st_rel(int* p, int v) {
    __hip_atomic_store(p, v, __ATOMIC_RELEASE, AQ);
}
__device__ __forceinline__ int ld_acq(int* p) {
    return __hip_atomic_load(p, __ATOMIC_ACQUIRE, AQ);
}
__device__ __forceinline__ void stf(float* p, float v) {
    __hip_atomic_store(p, v, __ATOMIC_RELAXED, AQ);
}
__device__ __forceinline__ float ldf(const float* p) {
    return __hip_atomic_load((float*)p, __ATOMIC_RELAXED, AQ);
}

// GEMV over one 128-k quarter for 2 rows. wreg = 16 uint4 of f16 weights (col tid),
// SH/SL = hi/lo half vectors of the 2 rows' activation slices (row0 uint4 0..15,
// row1 uint4 16..31). Accumulates hi/lo separately, fixed order.
__device__ __forceinline__ void gemv_q(const uint4* wreg, const uint4* SH,
                                       const uint4* SL, float bias,
                                       float& p0, float& p1) {
    float a0H = bias, a0L = 0.0f, a1H = bias, a1L = 0.0f;
    #pragma unroll
    for (int m = 0; m < 16; m++) {
        uint4 wv = wreg[m];
        uint4 h0 = SH[m],      l0 = SL[m];
        uint4 h1 = SH[16 + m], l1 = SL[16 + m];
        a0H = dot2f(wv.x, h0.x, a0H); a0H = dot2f(wv.y, h0.y, a0H);
        a0H = dot2f(wv.z, h0.z, a0H); a0H = dot2f(wv.w, h0.w, a0H);
        a0L = dot2f(wv.x, l0.x, a0L); a0L = dot2f(wv.y, l0.y, a0L);
        a0L = dot2f(wv.z, l0.z, a0L); a0L = dot2f(wv.w, l0.w, a0L);
        a1H = dot2f(wv.x, h1.x, a1H); a1H = dot2f(wv.y, h1.y, a1H);
        a1H = dot2f(wv.z, h1.z, a1H); a1H = dot2f(wv.w, h1.w, a1H);
        a1L = dot2f(wv.x, l1.x, a1L); a1L = dot2f(wv.y, l1.y, a1L);
        a1L = dot2f(wv.z, l1.z, a1L); a1L = dot2f(wv.w, l1.w, a1L);
    }
    p0 = a0H + a0L;
    p1 = a1H + a1L;
}

// Weight layouts:
//  WQ4[q][m][j] (q=0..3, m=0..15, j=0..1023): uint4 of f16 W[j][base..base+7],
//    base = (q<2 ? q*128 : 256+(q-2)*128) + 8m.  (quad kernel, k-quarter split)
//  WX4[m][j] m=0..31: cols 8m..8m+7 (x part)      (fallback kernel)
//  WH4[m][j] m=0..31: cols 256+8m..256+8m+7 (hx)  (fallback kernel)
//  biasc[1024] fp32.  quad_mode also zeroes the 16384-int flag region.
__global__ __launch_bounds__(256) void prep_kernel(
    const float* __restrict__ Wf, const float* __restrict__ Wi,
    const float* __restrict__ Wg, const float* __restrict__ Wo,
    const float* __restrict__ bf, const float* __restrict__ bi,
    const float* __restrict__ bg, const float* __restrict__ bo,
    int quad_mode,
    uint4* __restrict__ WQ4, uint4* __restrict__ WX4,
    uint4* __restrict__ WH4, float* __restrict__ biasc,
    int* __restrict__ flags)
{
    int idx = blockIdx.x * 256 + threadIdx.x;   // 0 .. 131071
    if (quad_mode && idx < 16384) {
        __hip_atomic_store(&flags[idx], 0, __ATOMIC_RELAXED, AQ);
    }
    if (idx < 1024) {
        int g = idx >> 8, h = idx & 255;
        const float* bb = (g == 0) ? bf : (g == 1) ? bi : (g == 2) ? bg : bo;
        biasc[idx] = bb[h];
    }
    if (quad_mode) {
        if (idx < 65536) {
            int q = idx >> 14, m = (idx >> 10) & 15, j = idx & 1023;
            int g = j >> 8, h = j & 255;
            const float* W = (g == 0) ? Wf : (g == 1) ? Wi : (g == 2) ? Wg : Wo;
            const float* row = W + h * (D_IN + H_DIM);
            int base = ((q < 2) ? q * 128 : 256 + (q - 2) * 128) + 8 * m;
            WQ4[idx] = pack8(row + base);
        } else {
            int e = idx - 65536;            // 0..65535
            int which = e >> 15;            // 0: WX4, 1: WH4
            int e2 = e & 32767;
            int m = e2 >> 10, j = e2 & 1023;
            int g = j >> 8, h = j & 255;
            const float* W = (g == 0) ? Wf : (g == 1) ? Wi : (g == 2) ? Wg : Wo;
            const float* row = W + h * (D_IN + H_DIM);
            if (which == 0) WX4[e2] = pack8(row + 8 * m);
            else            WH4[e2] = pack8(row + D_IN + 8 * m);
        }
    } else {
        if (idx < 32768) {
            int m = idx >> 10, j = idx & 1023;
            int g = j >> 8, h = j & 255;
            const float* W = (g == 0) ? Wf : (g == 1) ? Wi : (g == 2) ? Wg : Wo;
            WX4[idx] = pack8(W + h * (D_IN + H_DIM) + 8 * m);
        } else if (idx < 65536) {
            int e2 = idx - 32768;
            int m = e2 >> 10, j = e2 & 1023;
            int g = j >> 8, h = j & 255;
            const float* W = (g == 0) ? Wf : (g == 1) ? Wi : (g == 2) ? Wg : Wo;
            WH4[e2] = pack8(W + h * (D_IN + H_DIM) + D_IN + 8 * m);
        }
    }
}

// ---------------------------------------------------------------------------
// Quad kernel: 256 blocks = 64 quads x 4 roles; quad Q owns rows (2Q, 2Q+1).
//  q=0,1: x-part producers over k-halves of x; run ahead into a RING-deep LLC
//         ring, throttled by consumer progress counters.
//  q=2,3: h-part consumers over k-halves of h; exchange partials (parity
//         double-buffered) + redundant act/est/update (bitwise identical) so
//         no h crosses CUs.  Weights are register-resident (wreg[16] = 64 VGPR)
//         -> zero weight streaming. 1 block/CU forced by VGPR count (>64).
// ---------------------------------------------------------------------------
__global__ __launch_bounds__(1024, 1) void qlstm_quad_kernel(
    const float* __restrict__ x,
    const uint4* __restrict__ WQ4,
    const float* __restrict__ biasc,
    float* __restrict__ hpart,     // [64][2 cu][2 par][2 row][1024]
    float* __restrict__ xring,     // [64][2 cu][RING][2 row][1024]
    int* __restrict__ flags,       // xf: [Q*32+q] ; hf: 4096+ ; cf: 8192+
    const float* __restrict__ estW1, const float* __restrict__ estb1,
    const float* __restrict__ estW2, const float* __restrict__ estb2,
    const float* __restrict__ estW3, const float* __restrict__ estb3,
    float* __restrict__ out)
{
    __shared__ __align__(16) float gact[2 * NCOL];     // [row][1024] activated gates
    __shared__ float w1p[4 * 8 * H_DIM];               // permuted estW1
    __shared__ float sb1[32];
    __shared__ float sW2[128];
    __shared__ float sb2[16];
    __shared__ float sW3[16];
    __shared__ float sb3[4];
    __shared__ float escl[8];                          // [row][gate]
    __shared__ __align__(16) __half slh[2 * 128];      // hi of 2-row k-slice
    __shared__ __align__(16) __half sll[2 * 128];      // lo

    const int Q   = blockIdx.x >> 2;
    const int q   = blockIdx.x & 3;
    const int tid = threadIdx.x;

    // register-resident weight quarter: col tid, 128 k as 16 uint4
    uint4 wreg[16];
    {
        const uint4* wp = WQ4 + ((size_t)q << 14) + tid;
        #pragma unroll
        for (int m = 0; m < 16; m++) wreg[m] = wp[(size_t)m << 10];
    }

    const uint4* SH = (const uint4*)slh;
    const uint4* SL = (const uint4*)sll;

    if (q < 2) {
        // ------------------------- x producer -------------------------
        const int d0 = q * 128;
        float* myring = xring + (size_t)(Q * 2 + q) * (RING * 2048);
        int* myflag = &flags[Q * 32 + q];
        int* cfA = &flags[8192 + Q * 32 + 0];
        int* cfB = &flags[8192 + Q * 32 + 1];
        const float bload = (q == 0) ? biasc[tid] : 0.0f;

        float xv_nxt = 0.0f;
        if (tid < 256) {
            int r = tid >> 7, kk = tid & 127;
            xv_nxt = x[(size_t)(2 * Q + r) * D_IN + d0 + kk];   // t=0
        }
        for (int t = 0; t < T_STEPS; t++) {
            if (tid == 0) {
                for (;;) {
                    int ca = ld_acq(cfA), cb = ld_acq(cfB);
                    int cm = ca < cb ? ca : cb;
                    if (t - cm < RING) break;
                    __builtin_amdgcn_s_sleep(8);
                }
            }
            __syncthreads();     // slot free; also guards slh overwrite
            float xv = xv_nxt;
            if (tid < 256) {
                int r = tid >> 7, kk = tid & 127;
                __half hi = __float2half_rn(xv);
                slh[(r << 7) + kk] = hi;
                sll[(r << 7) + kk] = __float2half_rn(xv - __half2float(hi));
                if (t + 1 < T_STEPS)
                    xv_nxt = x[((size_t)(t + 1) * BATCH + (2 * Q + r)) * D_IN + d0 + kk];
            }
            __syncthreads();
            float p0, p1;
            gemv_q(wreg, SH, SL, bload, p0, p1);
            float* dst = myring + (t & (RING - 1)) * 2048;
            stf(&dst[tid], p0);
            stf(&dst[1024 + tid], p1);
            __syncthreads();     // vmcnt(0): stores at coherence point
            if (tid == 0) st_rel(myflag, t + 1);
        }
        return;
    }

    // ------------------------- h consumer -------------------------
    const int cu = q - 2;                 // 0: h[0..127], 1: h[128..255]
    const int kq = cu << 7;
    float* myhp_b   = hpart + (size_t)(Q * 2 + cu) * 4096;       // [par][row][1024]
    float* peerhp_b = hpart + (size_t)(Q * 2 + (1 - cu)) * 4096;
    int* myhf   = &flags[4096 + Q * 32 + cu];
    int* peerhf = &flags[4096 + Q * 32 + (1 - cu)];
    int* mycf   = &flags[8192 + Q * 32 + cu];
    int* xf0 = &flags[Q * 32 + 0];
    int* xf1 = &flags[Q * 32 + 1];
    const float* ring0 = xring + (size_t)(Q * 2 + 0) * (RING * 2048);
    const float* ring1 = xring + (size_t)(Q * 2 + 1) * (RING * 2048);

    // stage est params; permute w1 so lane-l float4 reads of gact are stride-1
    for (int i = tid; i < 4 * 8 * H_DIM; i += 1024) {
        int p = i & 255;
        int base = i & ~255;
        int h = 4 * (p & 63) + (p >> 6);
        w1p[i] = estW1[base + h];
    }
    if (tid < 32)  sb1[tid] = estb1[tid];
    if (tid < 128) sW2[tid] = estW2[tid];
    if (tid < 16)  { sb2[tid] = estb2[tid]; sW3[tid] = estW3[tid]; }
    if (tid < 4)   sb3[tid] = estb3[tid];
    if (tid < 256) { slh[tid] = __float2half(0.0f); sll[tid] = __float2half(0.0f); }
    float c_reg = 0.0f, h_reg = 0.0f;
    __syncthreads();

    for (int t = 0; t < T_STEPS; t++) {
        // own h-quarter partial (h from LDS slices, weights from regs)
        float p0, p1;
        gemv_q(wreg, SH, SL, 0.0f, p0, p1);
        const int par = t & 1;
        float* myhp = myhp_b + par * 2048;
        stf(&myhp[tid], p0);
        stf(&myhp[1024 + tid], p1);
        __syncthreads();                       // stores drained
        if (tid == 0) st_rel(myhf, t + 1);
        // wait peer h-partial + both x-partials
        if (tid == 0) {
            while (ld_acq(peerhf) < t + 1) __builtin_amdgcn_s_sleep(1);
        } else if (tid == 64) {
            while (ld_acq(xf0) < t + 1) __builtin_amdgcn_s_sleep(1);
        } else if (tid == 128) {
            while (ld_acq(xf1) < t + 1) __builtin_amdgcn_s_sleep(1);
        }
        __syncthreads();
        // gather + fixed-order sum: ((x0 + x1) + h_low) + h_high
        const int slot = t & (RING - 1);
        const float* r0p = ring0 + slot * 2048;
        const float* r1p = ring1 + slot * 2048;
        const float* pr  = peerhp_b + par * 2048;
        float xa0 = ldf(&r0p[tid]),        xb0 = ldf(&r1p[tid]);
        float xa1 = ldf(&r0p[1024 + tid]), xb1 = ldf(&r1p[1024 + tid]);
        float ph0 = ldf(&pr[tid]),         ph1 = ldf(&pr[1024 + tid]);
        float hA0 = (cu == 0) ? p0 : ph0,  hB0 = (cu == 0) ? ph0 : p0;
        float hA1 = (cu == 0) ? p1 : ph1,  hB1 = (cu == 0) ? ph1 : p1;
        float tot0 = ((xa0 + xb0) + hA0) + hB0;
        float tot1 = ((xa1 + xb1) + hA1) + hB1;
        const int gate = tid >> 8;
        gact[tid]        = (gate == 2) ? tanhf_(tot0) : sigmoidf_(tot0);
        gact[1024 + tid] = (gate == 2) ? tanhf_(tot1) : sigmoidf_(tot1);
        __syncthreads();

        // est MLP: waves 0..7 -> (row = w>>2, gate = w&3), redundant on both CUs
        if (tid < 512) {
            const int w_   = tid >> 6;
            const int row  = w_ >> 2, ge = w_ & 3;
            const int lane = tid & 63;
            float4 gv = ((const float4*)(gact + row * 1024 + (ge << 8)))[lane];
            float h1[8];
            #pragma unroll
            for (int j = 0; j < 8; j++) {
                const float* wr = &w1p[(ge * 8 + j) * H_DIM];
                float s = fmaf(gv.x, wr[lane],
                          fmaf(gv.y, wr[lane + 64],
                          fmaf(gv.z, wr[lane + 128], gv.w * wr[lane + 192])));
                #pragma unroll
                for (int m2 = 1; m2 < 64; m2 <<= 1) s += __shfl_xor(s, m2, 64);
                h1[j] = tanhf_(s + sb1[ge * 8 + j]);
            }
            float h2[4];
            #pragma unroll
            for (int j = 0; j < 4; j++) {
                float s = sb2[ge * 4 + j];
                #pragma unroll
                for (int p = 0; p < 8; p++) s = fmaf(h1[p], sW2[ge * 32 + j * 8 + p], s);
                h2[j] = tanhf_(s);
            }
            float s3 = sb3[ge];
            #pragma unroll
            for (int p = 0; p < 4; p++) s3 = fmaf(h2[p], sW3[ge * 4 + p], s3);
            if (lane == 0) escl[row * 4 + ge] = sigmoidf_(s3);
        }
        __syncthreads();

        // state update (redundant, bitwise identical on both consumer CUs)
        if (tid < 512) {
            const int r = tid >> 8, j = tid & 255;
            const float* ga = gact + r * 1024;
            const float* es = escl + r * 4;
            float f  = ga[j]       * es[0];
            float ii = ga[256 + j] * es[1];
            float gg = ga[512 + j] * es[2];
            float o  = ga[768 + j] * es[3];
            c_reg = fmaf(f, c_reg, ii * gg);
            h_reg = o * tanhf_(c_reg);
            if (r == cu)
                out[((size_t)t * BATCH + (2 * Q + r)) * H_DIM + j] = h_reg;
            if (j >= kq && j < kq + 128) {
                __half hi = __float2half_rn(h_reg);
                slh[(r << 7) + (j - kq)] = hi;
                sll[(r << 7) + (j - kq)] = __float2half_rn(h_reg - __half2float(hi));
            }
        }
        __syncthreads();                       // h slices + gather consumed
        if (tid == 0) st_rel(mycf, t + 1);     // ring slot t reusable
    }

    if (tid < 512) {
        const int r = tid >> 8, j = tid & 255;
        if (r == cu) {
            const size_t stacked = (size_t)T_STEPS * BATCH * H_DIM;
            out[stacked + (size_t)(2 * Q + r) * H_DIM + j] = h_reg;
            out[stacked + (size_t)BATCH * H_DIM + (size_t)(2 * Q + r) * H_DIM + j] = c_reg;
        }
    }
}

// ---------------------------------------------------------------------------
// Fallback (small workspace): round-1 single-block-per-row kernel, full k,
// x-GEMV computed on the fly.  Proven at 10.4 ms.
// ---------------------------------------------------------------------------
__global__ __launch_bounds__(1024) void qlstm_fallback_kernel(
    const float* __restrict__ x,
    const uint4* __restrict__ WX4,
    const uint4* __restrict__ WH4,
    const float* __restrict__ biasc,
    const float* __restrict__ estW1, const float* __restrict__ estb1,
    const float* __restrict__ estW2, const float* __restrict__ estb2,
    const float* __restrict__ estW3, const float* __restrict__ estb3,
    float* __restrict__ out)
{
    __shared__ __align__(16) __half hxh[H_DIM];
    __shared__ __align__(16) __half hxl[H_DIM];
    __shared__ __align__(16) __half cxh[D_IN];
    __shared__ __align__(16) __half cxl[D_IN];
    __shared__ __align__(16) float gact[NCOL];
    __shared__ float w1[4][8][H_DIM];
    __shared__ float sb1[32];
    __shared__ float sW2[128];
    __shared__ float sb2[16];
    __shared__ float sW3[16];
    __shared__ float sb3[4];
    __shared__ float escale[4];

    const int b    = blockIdx.x;
    const int tid  = threadIdx.x;
    const int w    = tid >> 6;
    const int lane = tid & 63;

    for (int i = tid; i < 4 * 8 * H_DIM; i += 1024) {
        int p = i & 255;
        int base = i & ~255;
        int h = 4 * (p & 63) + (p >> 6);
        ((float*)w1)[i] = estW1[base + h];
    }
    if (tid < 32)  sb1[tid] = estb1[tid];
    if (tid < 128) sW2[tid] = estW2[tid];
    if (tid < 16)  { sb2[tid] = estb2[tid]; sW3[tid] = estW3[tid]; }
    if (tid < 4)   sb3[tid] = estb3[tid];
    if (tid < H_DIM) {
        hxh[tid] = __float2half(0.0f);
        hxl[tid] = __float2half(0.0f);
    }
    float c_reg = 0.0f, h_reg = 0.0f;
    const float b_j = biasc[tid];
    __syncthreads();

    const uint4* hh = (const uint4*)hxh;
    const uint4* hl = (const uint4*)hxl;
    const uint4* xh = (const uint4*)cxh;
    const uint4* xl = (const uint4*)cxl;

    for (int t = 0; t < T_STEPS; t++) {
        float aH = b_j, aL = 0.0f;
        if (tid < D_IN) {
            float xv = x[((size_t)t * BATCH + b) * D_IN + tid];
            __half hi = __float2half_rn(xv);
            cxh[tid] = hi;
            cxl[tid] = __float2half_rn(xv - __half2float(hi));
        }
        __syncthreads();
        #pragma unroll 4
        for (int m = 0; m < 32; m++) {
            uint4 wv = WX4[(m << 10) + tid];
            uint4 hv = xh[m], lv = xl[m];
            aH = dot2f(wv.x, hv.x, aH); aH = dot2f(wv.y, hv.y, aH);
            aH = dot2f(wv.z, hv.z, aH); aH = dot2f(wv.w, hv.w, aH);
            aL = dot2f(wv.x, lv.x, aL); aL = dot2f(wv.y, lv.y, aL);
            aL = dot2f(wv.z, lv.z, aL); aL = dot2f(wv.w, lv.w, aL);
        }
        #pragma unroll 4
        for (int m = 0; m < 32; m++) {
            uint4 wv = WH4[(m << 10) + tid];
            uint4 hv = hh[m], lv = hl[m];
            aH = dot2f(wv.x, hv.x, aH); aH = dot2f(wv.y, hv.y, aH);
            aH = dot2f(wv.z, hv.z, aH); aH = dot2f(wv.w, hv.w, aH);
            aL = dot2f(wv.x, lv.x, aL); aL = dot2f(wv.y, lv.y, aL);
            aL = dot2f(wv.z, lv.z, aL); aL = dot2f(wv.w, lv.w, aL);
        }
        float acc = aH + aL;

        float v = (tid >= 512 && tid < 768) ? tanhf_(acc) : sigmoidf_(acc);
        gact[tid] = v;
        __syncthreads();

        if (tid < 256) {
            float4 gv = ((const float4*)(gact + (w << 8)))[lane];
            float h1[8];
            #pragma unroll
            for (int j = 0; j < 8; j++) {
                const float* wr = &w1[w][j][0];
                float s = fmaf(gv.x, wr[lane],
                          fmaf(gv.y, wr[lane + 64],
                          fmaf(gv.z, wr[lane + 128], gv.w * wr[lane + 192])));
                #pragma unroll
                for (int m2 = 1; m2 < 64; m2 <<= 1) s += __shfl_xor(s, m2, 64);
                h1[j] = tanhf_(s + sb1[w * 8 + j]);
            }
            float h2[4];
            #pragma unroll
            for (int j = 0; j < 4; j++) {
                float s = sb2[w * 4 + j];
                #pragma unroll
                for (int p = 0; p < 8; p++) s = fmaf(h1[p], sW2[w * 32 + j * 8 + p], s);
                h2[j] = tanhf_(s);
            }
            float s3 = sb3[w];
            #pragma unroll
            for (int p = 0; p < 4; p++) s3 = fmaf(h2[p], sW3[w * 4 + p], s3);
            if (lane == 0) escale[w] = sigmoidf_(s3);
        }
        __syncthreads();

        if (tid < 256) {
            float f  = gact[tid]       * escale[0];
            float ii = gact[256 + tid] * escale[1];
            float gg = gact[512 + tid] * escale[2];
            float o  = gact[768 + tid] * escale[3];
            c_reg = fmaf(f, c_reg, ii * gg);
            h_reg = o * tanhf_(c_reg);
            __half hi = __float2half_rn(h_reg);
            hxh[tid] = hi;
            hxl[tid] = __float2half_rn(h_reg - __half2float(hi));
            out[((size_t)t * BATCH + b) * H_DIM + tid] = h_reg;
        }
        __syncthreads();
    }

    if (tid < 256) {
        const size_t stacked = (size_t)T_STEPS * BATCH * H_DIM;
        out[stacked + (size_t)b * H_DIM + tid] = h_reg;
        out[stacked + (size_t)BATCH * H_DIM + (size_t)b * H_DIM + tid] = c_reg;
    }
}

extern "C" void kernel_launch(void* const* d_in, const int* in_sizes, int n_in,
                              void* d_out, int out_size, void* d_ws, size_t ws_size,
                              hipStream_t stream) {
    const float* x     = (const float*)d_in[0];
    const float* Wf    = (const float*)d_in[1];
    const float* bf    = (const float*)d_in[2];
    const float* Wi    = (const float*)d_in[3];
    const float* bi    = (const float*)d_in[4];
    const float* Wg    = (const float*)d_in[5];
    const float* bg    = (const float*)d_in[6];
    const float* Wo    = (const float*)d_in[7];
    const float* bo    = (const float*)d_in[8];
    const float* estW1 = (const float*)d_in[9];
    const float* estb1 = (const float*)d_in[10];
    const float* estW2 = (const float*)d_in[11];
    const float* estb2 = (const float*)d_in[12];
    const float* estW3 = (const float*)d_in[13];
    const float* estb3 = (const float*)d_in[14];

    // quad layout
    uint4* WQ4    = (uint4*)d_ws;                      // 65536 uint4 = 1 MB
    uint4* WX4q   = WQ4 + 65536;                       // 512 KB
    uint4* WH4q   = WX4q + 32768;                      // 512 KB
    float* biascq = (float*)(WH4q + 32768);            // 4 KB
    int*   flags  = (int*)(biascq + 1024);             // 64 KB
    float* hpart  = (float*)(flags + 16384);           // 64*2*2*2*1024 f = 2 MB
    float* xring  = hpart + (size_t)64 * 8192;         // 64*2*RING*2*1024 f = 4 MB
    const size_t need_quad = (size_t)131072 * 16 + 1024 * 4 + 16384 * 4 +
                             (size_t)64 * 8192 * 4 + (size_t)64 * 2 * RING * 2048 * 4;

    if (ws_size >= need_quad) {
        prep_kernel<<<512, 256, 0, stream>>>(Wf, Wi, Wg, Wo, bf, bi, bg, bo,
                                             1, WQ4, WX4q, WH4q, biascq, flags);
        qlstm_quad_kernel<<<256, 1024, 0, stream>>>(
            x, WQ4, biascq, hpart, xring, flags,
            estW1, estb1, estW2, estb2, estW3, estb3, (float*)d_out);
    } else {
        // compact fallback layout (fits proven >=1.6 MB workspace)
        uint4* WX4f   = (uint4*)d_ws;                  // 512 KB
        uint4* WH4f   = WX4f + 32768;                  // 512 KB
        float* biascf = (float*)(WH4f + 32768);        // 4 KB
        prep_kernel<<<512, 256, 0, stream>>>(Wf, Wi, Wg, Wo, bf, bi, bg, bo,
                                             0, WX4f, WX4f, WH4f, biascf, (int*)biascf);
        qlstm_fallback_kernel<<<BATCH, 1024, 0, stream>>>(
            x, WX4f, WH4f, biascf,
            estW1, estb1, estW2, estb2, estW3, estb3, (float*)d_out);
    }
}

// Round 4
// 10636.974 us; speedup vs baseline: 1.9002x; 1.9002x over previous
//
#include <hip/hip_runtime.h>
#include <hip/hip_fp16.h>
#include <math.h>

// Problem dims
#define T_STEPS 1024
#define BATCH   128
#define D_IN    256
#define H_DIM   256
#define NCOL    1024  // 4 gates * H
#define CH      16    // x-precompute chunk (steps)

typedef _Float16 half2_t __attribute__((ext_vector_type(2)));

__device__ __forceinline__ float sigmoidf_(float x) {
    return 1.0f / (1.0f + __expf(-x));
}

__device__ __forceinline__ float tanhf_(float x) {
    float ax = fabsf(x);
    float t = __expf(-2.0f * ax);
    float r = (1.0f - t) / (1.0f + t);
    return copysignf(r, x);
}

// 2-way f16 dot with f32 accumulate: acc += w.x*h.x + w.y*h.y
__device__ __forceinline__ float dot2f(unsigned int w, unsigned int h, float acc) {
#if __has_builtin(__builtin_amdgcn_fdot2)
    return __builtin_amdgcn_fdot2(__builtin_bit_cast(half2_t, w),
                                  __builtin_bit_cast(half2_t, h), acc, false);
#else
    __half2 wv = *(__half2*)&w, hv = *(__half2*)&h;
    acc = fmaf(__half2float(wv.x), __half2float(hv.x), acc);
    return fmaf(__half2float(wv.y), __half2float(hv.y), acc);
#endif
}

__device__ __forceinline__ unsigned int packh2(float a, float b) {
    __half2 p = __floats2half2_rn(a, b);
    return *(unsigned int*)&p;
}

__device__ __forceinline__ uint4 pack8(const float* p) {
    return make_uint4(packh2(p[0], p[1]), packh2(p[2], p[3]),
                      packh2(p[4], p[5]), packh2(p[6], p[7]));
}

// Layouts (j = gate*256 + h, m = 0..31 indexes k-octets):
//   WX4[m*1024 + j] = uint4 of f16 W[j][8m..8m+7]        (x part)
//   WH4[m*1024 + j] = uint4 of f16 W[j][256+8m..256+8m+7] (hx part)
//   biasc[1024] fp32
__global__ __launch_bounds__(256) void prep_kernel(
    const float* __restrict__ Wf, const float* __restrict__ Wi,
    const float* __restrict__ Wg, const float* __restrict__ Wo,
    const float* __restrict__ bf, const float* __restrict__ bi,
    const float* __restrict__ bg, const float* __restrict__ bo,
    uint4* __restrict__ WX4, uint4* __restrict__ WH4,
    float* __restrict__ biasc)
{
    int idx = blockIdx.x * 256 + threadIdx.x;   // 0 .. 32767
    int m = idx >> 10;
    int j = idx & 1023;
    int g = j >> 8;
    int h = j & 255;
    const float* W = (g == 0) ? Wf : (g == 1) ? Wi : (g == 2) ? Wg : Wo;
    const float* row = W + h * (D_IN + H_DIM);
    WX4[idx] = pack8(row + 8 * m);
    WH4[idx] = pack8(row + D_IN + 8 * m);
    if (idx < NCOL) {
        const float* bb = (g == 0) ? bf : (g == 1) ? bi : (g == 2) ? bg : bo;
        biasc[idx] = bb[h];
    }
}

// One block per batch row; 1024 threads (16 waves). Thread tid owns column
// j = tid (j = gate*256 + h).
// Every CH steps: x-part chunk GEMM in registers — stream WX once, x read as
// wave-uniform f32 from global (L1-hot), accumulate pacc[CH] in f32 FMA.
// Steady step: stream only WH (512 KB); h via hi/lo f16 dot2 from LDS.
__global__ __launch_bounds__(1024) void qlstm_kernel(
    const float* __restrict__ x,
    const uint4* __restrict__ WX4,
    const uint4* __restrict__ WH4,
    const float* __restrict__ biasc,
    const float* __restrict__ estW1, const float* __restrict__ estb1,
    const float* __restrict__ estW2, const float* __restrict__ estb2,
    const float* __restrict__ estW3, const float* __restrict__ estb3,
    float* __restrict__ out)
{
    __shared__ __align__(16) __half hxh[H_DIM];   // hi(hx)
    __shared__ __align__(16) __half hxl[H_DIM];   // lo(hx)
    __shared__ __align__(16) float gact[NCOL];    // activated gates
    __shared__ float w1[4 * 8 * H_DIM];  // estW1 permuted: [.][.][q*64+l] = h=4l+q
    __shared__ float sb1[32];
    __shared__ float sW2[128];
    __shared__ float sb2[16];
    __shared__ float sW3[16];
    __shared__ float sb3[4];
    __shared__ float escale[4];

    const int b    = blockIdx.x;
    const int tid  = threadIdx.x;
    const int w    = tid >> 6;
    const int lane = tid & 63;

    // stage est params; permute w1 so lane-l float4 reads of gact are stride-1
    for (int i = tid; i < 4 * 8 * H_DIM; i += 1024) {
        int p = i & 255;
        int base = i & ~255;
        int h = 4 * (p & 63) + (p >> 6);
        w1[i] = estW1[base + h];
    }
    if (tid < 32)  sb1[tid] = estb1[tid];
    if (tid < 128) sW2[tid] = estW2[tid];
    if (tid < 16)  { sb2[tid] = estb2[tid]; sW3[tid] = estW3[tid]; }
    if (tid < 4)   sb3[tid] = estb3[tid];
    if (tid < H_DIM) {
        hxh[tid] = __float2half(0.0f);
        hxl[tid] = __float2half(0.0f);
    }
    float c_reg = 0.0f, h_reg = 0.0f;
    const float b_j = biasc[tid];
    __syncthreads();

    const uint4* hh = (const uint4*)hxh;   // 32 x (8 halves): k = 8m..8m+7
    const uint4* hl = (const uint4*)hxl;

    float pacc[CH];

    for (int t0 = 0; t0 < T_STEPS; t0 += CH) {
        // ---- chunk phase: pacc[s] = bias + Wx . x[t0+s], pure registers ----
        #pragma unroll
        for (int s = 0; s < CH; s++) pacc[s] = b_j;
        {
            const float* xb = x + ((size_t)t0 * BATCH + b) * D_IN;
            for (int m = 0; m < 32; m++) {
                uint4 wv = WX4[(m << 10) + tid];
                __half2 q0 = *(__half2*)&wv.x, q1 = *(__half2*)&wv.y;
                __half2 q2 = *(__half2*)&wv.z, q3 = *(__half2*)&wv.w;
                float w0 = __half2float(q0.x), w1f = __half2float(q0.y);
                float w2 = __half2float(q1.x), w3 = __half2float(q1.y);
                float w4 = __half2float(q2.x), w5 = __half2float(q2.y);
                float w6 = __half2float(q3.x), w7 = __half2float(q3.y);
                #pragma unroll
                for (int s = 0; s < CH; s++) {
                    // wave-uniform f32 reads of this row's x octet (L1-hot)
                    const float* xr = xb + (size_t)s * (BATCH * D_IN) + (m << 3);
                    float4 xa = *(const float4*)xr;
                    float4 xc = *(const float4*)(xr + 4);
                    float a = pacc[s];
                    a = fmaf(w0, xa.x, a); a = fmaf(w1f, xa.y, a);
                    a = fmaf(w2, xa.z, a); a = fmaf(w3, xa.w, a);
                    a = fmaf(w4, xc.x, a); a = fmaf(w5, xc.y, a);
                    a = fmaf(w6, xc.z, a); a = fmaf(w7, xc.w, a);
                    pacc[s] = a;
                }
            }
        }

        // ---- 16 recurrent steps consuming pacc ----
        #pragma unroll 1
        for (int s = 0; s < CH; s++) {
            const int t = t0 + s;
            float aH = pacc[s], aL = 0.0f;
            #pragma unroll 4
            for (int m = 0; m < 32; m++) {
                uint4 wv = WH4[(m << 10) + tid];
                uint4 hv = hh[m], lv = hl[m];
                aH = dot2f(wv.x, hv.x, aH); aH = dot2f(wv.y, hv.y, aH);
                aH = dot2f(wv.z, hv.z, aH); aH = dot2f(wv.w, hv.w, aH);
                aL = dot2f(wv.x, lv.x, aL); aL = dot2f(wv.y, lv.y, aL);
                aL = dot2f(wv.z, lv.z, aL); aL = dot2f(wv.w, lv.w, aL);
            }
            float acc = aH + aL;

            // activation: gate 2 (tid 512..767) tanh, others sigmoid
            float v = (tid >= 512 && tid < 768) ? tanhf_(acc) : sigmoidf_(acc);
            gact[tid] = v;
            __syncthreads();   // A: gates visible

            // est MLP for gate w: waves 0..3, H->8 (wave-reduced) ->4 ->1
            if (tid < 256) {
                float4 gv = ((const float4*)(gact + (w << 8)))[lane];
                float h1[8];
                #pragma unroll
                for (int j = 0; j < 8; j++) {
                    const float* wr = &w1[(w * 8 + j) * H_DIM];
                    float sacc = fmaf(gv.x, wr[lane],
                                 fmaf(gv.y, wr[lane + 64],
                                 fmaf(gv.z, wr[lane + 128], gv.w * wr[lane + 192])));
                    #pragma unroll
                    for (int m2 = 1; m2 < 64; m2 <<= 1) sacc += __shfl_xor(sacc, m2, 64);
                    h1[j] = tanhf_(sacc + sb1[w * 8 + j]);
                }
                float h2[4];
                #pragma unroll
                for (int j = 0; j < 4; j++) {
                    float sacc = sb2[w * 4 + j];
                    #pragma unroll
                    for (int q = 0; q < 8; q++)
                        sacc = fmaf(h1[q], sW2[w * 32 + j * 8 + q], sacc);
                    h2[j] = tanhf_(sacc);
                }
                float s3 = sb3[w];
                #pragma unroll
                for (int q = 0; q < 4; q++) s3 = fmaf(h2[q], sW3[w * 4 + q], s3);
                if (lane == 0) escale[w] = sigmoidf_(s3);
            }
            __syncthreads();   // B: escale visible

            // state update: thread tid < 256 owns h = tid
            if (tid < 256) {
                float f  = gact[tid]       * escale[0];
                float ii = gact[256 + tid] * escale[1];
                float gg = gact[512 + tid] * escale[2];
                float o  = gact[768 + tid] * escale[3];
                c_reg = fmaf(f, c_reg, ii * gg);
                h_reg = o * tanhf_(c_reg);
                __half hi = __float2half_rn(h_reg);
                hxh[tid] = hi;
                hxl[tid] = __float2half_rn(h_reg - __half2float(hi));
                out[((size_t)t * BATCH + b) * H_DIM + tid] = h_reg;
            }
            __syncthreads();   // C: new hx visible to all waves
        }
    }

    if (tid < 256) {
        const size_t stacked = (size_t)T_STEPS * BATCH * H_DIM;
        out[stacked + (size_t)b * H_DIM + tid] = h_reg;
        out[stacked + (size_t)BATCH * H_DIM + (size_t)b * H_DIM + tid] = c_reg;
    }
}

extern "C" void kernel_launch(void* const* d_in, const int* in_sizes, int n_in,
                              void* d_out, int out_size, void* d_ws, size_t ws_size,
                              hipStream_t stream) {
    const float* x     = (const float*)d_in[0];
    const float* Wf    = (const float*)d_in[1];
    const float* bf    = (const float*)d_in[2];
    const float* Wi    = (const float*)d_in[3];
    const float* bi    = (const float*)d_in[4];
    const float* Wg    = (const float*)d_in[5];
    const float* bg    = (const float*)d_in[6];
    const float* Wo    = (const float*)d_in[7];
    const float* bo    = (const float*)d_in[8];
    const float* estW1 = (const float*)d_in[9];
    const float* estb1 = (const float*)d_in[10];
    const float* estW2 = (const float*)d_in[11];
    const float* estb2 = (const float*)d_in[12];
    const float* estW3 = (const float*)d_in[13];
    const float* estb3 = (const float*)d_in[14];

    uint4* WX4   = (uint4*)d_ws;                 // 32768 uint4 = 512 KB
    uint4* WH4   = WX4 + 32768;                  // 512 KB
    float* biasc = (float*)(WH4 + 32768);        // 4 KB

    prep_kernel<<<128, 256, 0, stream>>>(Wf, Wi, Wg, Wo, bf, bi, bg, bo,
                                         WX4, WH4, biasc);
    qlstm_kernel<<<BATCH, 1024, 0, stream>>>(
        x, WX4, WH4, biasc,
        estW1, estb1, estW2, estb2, estW3, estb3, (float*)d_out);
}